// Round 10
// baseline (399.883 us; speedup 1.0000x reference)
//
#include <hip/hip_runtime.h>
#include <math.h>

// =====================================================================
// 3-layer GAT (PyG GATConv) on MI355X.
// R10: same structure as R9 (U=W·a fused scores, hi/lo bf16 planes,
// 2-MFMA GEMM with double-buffered LDS B) but the prefetch staging
// array is statically indexed -> stays in VGPRs (R9 spilled it to
// scratch: 103 MB WRITE_SIZE, the regression).
// Values flow bf16; logits fp32-exact end-to-end.
// =====================================================================

#define NEG_SLOPE 0.2f

typedef unsigned short u16;
typedef short bf16x8 __attribute__((ext_vector_type(8)));
typedef float floatx4 __attribute__((ext_vector_type(4)));

__device__ __forceinline__ float b2f(u16 u) {
    return __uint_as_float(((unsigned int)u) << 16);
}
__device__ __forceinline__ u16 f2b(float f) {
    unsigned int u = __float_as_uint(f);
    unsigned int r = (u + 0x7fffu + ((u >> 16) & 1u)) >> 16;   // RNE
    return (u16)r;
}

// ---------------- CSR build ----------------

__global__ __launch_bounds__(256) void edge_count(const int* __restrict__ ei, int E, int n,
                                                  int* __restrict__ deg) {
    int e = blockIdx.x * blockDim.x + threadIdx.x;
    int Etot = E + n;
    if (e >= Etot) return;
    int dst = (e < E) ? ei[E + e] : (e - E);   // self-loop for e >= E
    atomicAdd(&deg[dst], 1);
}

__global__ __launch_bounds__(256) void scan_partials(const int* __restrict__ deg,
                                                     int* __restrict__ partial, int n) {
    __shared__ int red[256];
    int i0 = blockIdx.x * 1024 + threadIdx.x * 4;
    int s = 0;
#pragma unroll
    for (int r = 0; r < 4; ++r) s += (i0 + r < n) ? deg[i0 + r] : 0;
    red[threadIdx.x] = s;
    __syncthreads();
    for (int off = 128; off > 0; off >>= 1) {
        if (threadIdx.x < off) red[threadIdx.x] += red[threadIdx.x + off];
        __syncthreads();
    }
    if (threadIdx.x == 0) partial[blockIdx.x] = red[0];
}

__global__ __launch_bounds__(128) void scan_mid(int* __restrict__ partial, int nb,
                                                int* __restrict__ offs, int n) {
    __shared__ int s[128];
    int v = (threadIdx.x < nb) ? partial[threadIdx.x] : 0;
    s[threadIdx.x] = v;
    __syncthreads();
    for (int off = 1; off < 128; off <<= 1) {
        int t = (threadIdx.x >= off) ? s[threadIdx.x - off] : 0;
        __syncthreads();
        s[threadIdx.x] += t;
        __syncthreads();
    }
    if (threadIdx.x < nb) partial[threadIdx.x] = s[threadIdx.x] - v;   // exclusive
    if (threadIdx.x == nb - 1) offs[n] = s[threadIdx.x];               // total
}

__global__ __launch_bounds__(256) void scan_final(const int* __restrict__ deg,
                                                  const int* __restrict__ partial,
                                                  int* __restrict__ offs,
                                                  int* __restrict__ cursor, int n) {
    __shared__ int s[256];
    int i0 = blockIdx.x * 1024 + threadIdx.x * 4;
    int v[4];
    int sum = 0;
#pragma unroll
    for (int r = 0; r < 4; ++r) {
        v[r] = (i0 + r < n) ? deg[i0 + r] : 0;
        sum += v[r];
    }
    s[threadIdx.x] = sum;
    __syncthreads();
    for (int off = 1; off < 256; off <<= 1) {
        int t = (threadIdx.x >= off) ? s[threadIdx.x - off] : 0;
        __syncthreads();
        s[threadIdx.x] += t;
        __syncthreads();
    }
    int excl = s[threadIdx.x] - sum + partial[blockIdx.x];
#pragma unroll
    for (int r = 0; r < 4; ++r) {
        if (i0 + r < n) { offs[i0 + r] = excl; cursor[i0 + r] = excl; }
        excl += v[r];
    }
}

__global__ __launch_bounds__(256) void edge_fill(const int* __restrict__ ei, int E, int n,
                                                 int* __restrict__ cursor,
                                                 int* __restrict__ csr) {
    int e = blockIdx.x * blockDim.x + threadIdx.x;
    int Etot = E + n;
    if (e >= Etot) return;
    int src, dst;
    if (e < E) { src = ei[e]; dst = ei[E + e]; }
    else       { src = e - E; dst = e - E; }
    int pos = atomicAdd(&cursor[dst], 1);
    csr[pos] = src;
}

// -------- Pack W (hi bf16 only) into MFMA-fragment-major layout ----------
// Unit u = kb*CT*64 + ct*64 + lane holds 8 bf16: W[kb*32+(lane>>4)*8+j][ct*16+(lane&15)].

__global__ __launch_bounds__(256) void pack_hi(const float* __restrict__ W,
                                               u16* __restrict__ Bh, int N) {
    int CT = N / 16;
    int idx = blockIdx.x * blockDim.x + threadIdx.x;
    if (idx >= 8 * CT * 64) return;
    int lane = idx & 63;
    int ctkb = idx >> 6;
    int ct = ctkb % CT;
    int kb = ctkb / CT;
    int col = ct * 16 + (lane & 15);
    int k0 = kb * 32 + (lane >> 4) * 8;
#pragma unroll
    for (int j = 0; j < 8; ++j)
        Bh[(size_t)idx * 8 + j] = f2b(W[(size_t)(k0 + j) * N + col]);
}

// -------- U = W·a (per-head score vectors in input space), fp32 exact ----
// U[v][k], v in [0,HEADS) = src heads, [HEADS,2*HEADS) = dst heads.

__global__ __launch_bounds__(64) void make_u(const float* __restrict__ W,
                                             const float* __restrict__ as,
                                             const float* __restrict__ ad,
                                             float* __restrict__ U, int C, int HEADS) {
    int k = blockIdx.x * 64 + threadIdx.x;
    if (k >= 256) return;
    const float* wr = W + (size_t)k * (HEADS * C);
    for (int h = 0; h < HEADS; ++h) {
        float s = 0.f, d = 0.f;
        for (int c = 0; c < C; ++c) {
            float wv = wr[h * C + c];
            s = fmaf(wv, as[h * C + c], s);
            d = fmaf(wv, ad[h * C + c], d);
        }
        U[h * 256 + k] = s;
        U[(HEADS + h) * 256 + k] = d;
    }
}

// ------- Layer-1 linear (K=3) + fused scores; writes bf16 shadow ---------

__global__ __launch_bounds__(256) void linear1(const float* __restrict__ x,
                                               const float* __restrict__ W,
                                               const float* __restrict__ asrc,
                                               const float* __restrict__ adst,
                                               u16* __restrict__ Hb,
                                               float* __restrict__ ssrc,
                                               float* __restrict__ sdst, int n) {
    int node = blockIdx.x;
    if (node >= n) return;
    int c = threadIdx.x;
    int head = c >> 6, lane = c & 63;
    float x0 = x[node * 3 + 0], x1 = x[node * 3 + 1], x2 = x[node * 3 + 2];
    float v = fmaf(x0, W[c], fmaf(x1, W[256 + c], x2 * W[512 + c]));
    Hb[(size_t)node * 256 + c] = f2b(v);
    float va = v * asrc[c];
    float vb = v * adst[c];
#pragma unroll
    for (int o = 32; o > 0; o >>= 1) {
        va += __shfl_xor(va, o);
        vb += __shfl_xor(vb, o);
    }
    if (lane == 0) { ssrc[node * 4 + head] = va; sdst[node * 4 + head] = vb; }
}

// ------- Lean MFMA GEMM: Hb = bf16( (Ahi+Alo) · Whi^T ) ------------------
// A pre-split hi/lo bf16 planes [n][256]; B fragment-major bf16.
// Double-buffered LDS B staging (statically-indexed register prefetch) +
// A register prefetch; one barrier per k-step.
// Fragments: A[m=lane&15][k=(lane>>4)*8+j]; D reg r -> row (l>>4)*4+r, col l&15.

template <int CT>
__global__ __launch_bounds__(256) void gemm_lds(const u16* __restrict__ Ahi,
                                                const u16* __restrict__ Alo,
                                                const u16* __restrict__ Bh,
                                                u16* __restrict__ Hb, int n) {
    constexpr int UN = CT * 64;                 // 16-byte units per k-slice
    constexpr int SU = (UN + 255) / 256;        // units per thread (static)
    __shared__ __align__(16) u16 sB[2][UN * 8];
    int t = threadIdx.x;
    int w = t >> 6, l = t & 63;
    int m0 = blockIdx.x * 64 + w * 16;
    int lm = l & 15, q = l >> 4;
    floatx4 acc[CT] = {};
    int arow = min(m0 + lm, n - 1);
    const u16* ahp = Ahi + (size_t)arow * 256 + q * 8;
    const u16* alp = Alo + (size_t)arow * 256 + q * 8;

    // prologue: stage slice 0, load A frag 0
#pragma unroll
    for (int i = 0; i < SU; ++i) {
        int u = t + i * 256;
        if (u < UN) *(uint4*)&sB[0][u * 8] = *(const uint4*)&Bh[(size_t)u * 8];
    }
    bf16x8 ahi = *(const bf16x8*)(ahp);
    bf16x8 alo = *(const bf16x8*)(alp);
    __syncthreads();

    for (int kb = 0; kb < 8; ++kb) {
        int cur = kb & 1;
        uint4 st[SU];
        bf16x8 nahi = ahi, nalo = alo;
        if (kb < 7) {                     // prefetch next B slice + next A frag
#pragma unroll
            for (int i = 0; i < SU; ++i) {
                int u = t + i * 256;
                if (u < UN)
                    st[i] = *(const uint4*)&Bh[((size_t)(kb + 1) * UN + u) * 8];
            }
            nahi = *(const bf16x8*)(ahp + (kb + 1) * 32);
            nalo = *(const bf16x8*)(alp + (kb + 1) * 32);
        }
#pragma unroll
        for (int ct = 0; ct < CT; ++ct) {
            bf16x8 bhi = *(const bf16x8*)&sB[cur][(ct * 64 + l) * 8];
            acc[ct] = __builtin_amdgcn_mfma_f32_16x16x32_bf16(ahi, bhi, acc[ct], 0, 0, 0);
            acc[ct] = __builtin_amdgcn_mfma_f32_16x16x32_bf16(alo, bhi, acc[ct], 0, 0, 0);
        }
        if (kb < 7) {
#pragma unroll
            for (int i = 0; i < SU; ++i) {
                int u = t + i * 256;
                if (u < UN) *(uint4*)&sB[cur ^ 1][u * 8] = st[i];
            }
            ahi = nahi; alo = nalo;
        }
        __syncthreads();
    }
#pragma unroll
    for (int ct = 0; ct < CT; ++ct)
#pragma unroll
        for (int r = 0; r < 4; ++r) {
            int row = m0 + q * 4 + r;
            if (row < n)
                Hb[(size_t)row * (CT * 16) + ct * 16 + lm] = f2b(acc[ct][r]);
        }
}

// ---------------- Merged 4-head aggregation (layers 1 & 2) ----------------
// One wave per dst node; bf16 value gathers, fp32 logits/accum.
// Epilogue: writes hi/lo bf16 planes of the relu'd output AND next-layer
// scores p[v] = g·U[v] (fp32-exact), NU = 2*heads_next.

template <int NU>
__global__ __launch_bounds__(256) void gat_aggregate_m4(const u16* __restrict__ Hb,
                                                        const float* __restrict__ ssrc,
                                                        const float* __restrict__ sdst,
                                                        const int* __restrict__ offs,
                                                        const int* __restrict__ csr,
                                                        const float* __restrict__ bias,
                                                        const float* __restrict__ U,
                                                        u16* __restrict__ Ghi,
                                                        u16* __restrict__ Glo,
                                                        float* __restrict__ sOs,
                                                        float* __restrict__ sOd, int n) {
    int node = blockIdx.x * 4 + (threadIdx.x >> 6);
    int lane = threadIdx.x & 63;
    if (node >= n) return;
    const int hB = lane & 3;
    const int eL = lane >> 2;
    const int hA = lane >> 4;
    int beg = offs[node], end = offs[node + 1];
    float sd = sdst[node * 4 + hB];
    float m = -INFINITY, l = 0.f;
    float4 acc = make_float4(0.f, 0.f, 0.f, 0.f);

    for (int base = beg; base < end; base += 16) {
        int j = base + eL;
        bool valid = (j < end);
        int sj = valid ? csr[j] : 0;
        float logit = -INFINITY;
        if (valid) {
            float xv = ssrc[sj * 4 + hB] + sd;
            logit = (xv > 0.f) ? xv : NEG_SLOPE * xv;
        }
        float cm = logit;
        cm = fmaxf(cm, __shfl_xor(cm, 4));
        cm = fmaxf(cm, __shfl_xor(cm, 8));
        cm = fmaxf(cm, __shfl_xor(cm, 16));
        cm = fmaxf(cm, __shfl_xor(cm, 32));
        float nm = fmaxf(m, cm);
        float scale = __expf(m - nm);       // m=-inf -> 0
        float ex = valid ? __expf(logit - nm) : 0.f;
        float es = ex;
        es += __shfl_xor(es, 4);
        es += __shfl_xor(es, 8);
        es += __shfl_xor(es, 16);
        es += __shfl_xor(es, 32);
        l = l * scale + es;
        m = nm;
        float sA = __shfl(scale, hA);
        acc.x *= sA; acc.y *= sA; acc.z *= sA; acc.w *= sA;

        int cnt = min(16, end - base);
        for (int t = 0; t < cnt; t += 4) {
#pragma unroll
            for (int u = 0; u < 4; ++u) {
                int tt = t + u;
                float a = __shfl(ex, tt * 4 + hA);   // 0 for invalid edges
                int s = __shfl(sj, tt * 4);          // 0 for invalid (safe addr)
                ushort4 hv = *(const ushort4*)&Hb[(size_t)s * 256 + lane * 4];
                acc.x = fmaf(a, b2f(hv.x), acc.x);
                acc.y = fmaf(a, b2f(hv.y), acc.y);
                acc.z = fmaf(a, b2f(hv.z), acc.z);
                acc.w = fmaf(a, b2f(hv.w), acc.w);
            }
        }
    }
    float lf = __shfl(l, hA);
    float inv = 1.f / lf;
    const float4 bv = *(const float4*)&bias[lane * 4];
    float4 o;
    o.x = fmaxf(fmaf(acc.x, inv, bv.x), 0.f);   // relu
    o.y = fmaxf(fmaf(acc.y, inv, bv.y), 0.f);
    o.z = fmaxf(fmaf(acc.z, inv, bv.z), 0.f);
    o.w = fmaxf(fmaf(acc.w, inv, bv.w), 0.f);
    // hi/lo bf16 planes (fp32-equivalent for the next GEMM)
    ushort4 h4, l4;
    h4.x = f2b(o.x); l4.x = f2b(o.x - b2f(h4.x));
    h4.y = f2b(o.y); l4.y = f2b(o.y - b2f(h4.y));
    h4.z = f2b(o.z); l4.z = f2b(o.z - b2f(h4.z));
    h4.w = f2b(o.w); l4.w = f2b(o.w - b2f(h4.w));
    *(ushort4*)&Ghi[(size_t)node * 256 + lane * 4] = h4;
    *(ushort4*)&Glo[(size_t)node * 256 + lane * 4] = l4;
    // next-layer scores: p[v] = g · U[v]   (fp32-exact logit path)
    float p[NU];
#pragma unroll
    for (int v = 0; v < NU; ++v) {
        const float4 uv = *(const float4*)&U[v * 256 + lane * 4];
        p[v] = o.x * uv.x + o.y * uv.y + o.z * uv.z + o.w * uv.w;
#pragma unroll
        for (int s = 32; s > 0; s >>= 1) p[v] += __shfl_xor(p[v], s);
    }
#pragma unroll
    for (int v = 0; v < NU; ++v) {
        if (lane == v) {
            if (v < NU / 2) sOs[node * (NU / 2) + v] = p[v];
            else            sOd[node * (NU / 2) + (v - NU / 2)] = p[v];
        }
    }
}

// ---------------- Single-head aggregation (layer 3, C=32, no relu) --------

__global__ __launch_bounds__(256) void gat_aggregate_h1(const u16* __restrict__ Hb,
                                                        const float* __restrict__ ssrc,
                                                        const float* __restrict__ sdst,
                                                        const int* __restrict__ offs,
                                                        const int* __restrict__ csr,
                                                        const float* __restrict__ bias,
                                                        float* __restrict__ out, int n) {
    int node = blockIdx.x * 4 + (threadIdx.x >> 6);
    int lane = threadIdx.x & 63;
    if (node >= n) return;
    int beg = offs[node], end = offs[node + 1];
    float sd = sdst[node];
    float m = -INFINITY, l = 0.f, acc = 0.f;

    for (int base = beg; base < end; base += 64) {
        int j = base + lane;
        bool valid = (j < end);
        int sj = valid ? csr[j] : 0;
        float logit = -INFINITY;
        if (valid) {
            float xv = ssrc[sj] + sd;
            logit = (xv > 0.f) ? xv : NEG_SLOPE * xv;
        }
        float cm = logit;
#pragma unroll
        for (int o = 32; o > 0; o >>= 1) cm = fmaxf(cm, __shfl_xor(cm, o));
        float nm = fmaxf(m, cm);
        float scale = __expf(m - nm);
        float ex = valid ? __expf(logit - nm) : 0.f;
        float es = ex;
#pragma unroll
        for (int o = 32; o > 0; o >>= 1) es += __shfl_xor(es, o);
        l = l * scale + es;
        m = nm;
        acc *= scale;
        int cnt = min(64, end - base);
        for (int t = 0; t < cnt; t += 4) {
#pragma unroll
            for (int u = 0; u < 4; ++u) {
                float a = __shfl(ex, t + u);
                int s = __shfl(sj, t + u);
                if (lane < 32) acc = fmaf(a, b2f(Hb[(size_t)s * 32 + lane]), acc);
            }
        }
    }
    if (lane < 32) out[(size_t)node * 32 + lane] = acc / l + bias[lane];
}

// ---------------- Launch ----------------

extern "C" void kernel_launch(void* const* d_in, const int* in_sizes, int n_in,
                              void* d_out, int out_size, void* d_ws, size_t ws_size,
                              hipStream_t stream) {
    const float* x   = (const float*)d_in[0];
    const int*   ei  = (const int*)d_in[1];
    const float* W1  = (const float*)d_in[2];
    const float* as1 = (const float*)d_in[3];
    const float* ad1 = (const float*)d_in[4];
    const float* b1  = (const float*)d_in[5];
    const float* W2  = (const float*)d_in[6];
    const float* as2 = (const float*)d_in[7];
    const float* ad2 = (const float*)d_in[8];
    const float* b2  = (const float*)d_in[9];
    const float* W3  = (const float*)d_in[10];
    const float* as3 = (const float*)d_in[11];
    const float* ad3 = (const float*)d_in[12];
    const float* b3  = (const float*)d_in[13];
    float* out = (float*)d_out;

    const int n = in_sizes[0] / 3;     // 50000
    const int E = in_sizes[1] / 2;     // 400000
    const int Etot = E + n;            // with self-loops

    // workspace layout
    char* ws = (char*)d_ws;
    u16* Hb   = (u16*)ws;    ws += (size_t)n * 256 * sizeof(u16);   // 25.6 MB shadow
    u16* Ghi  = (u16*)ws;    ws += (size_t)n * 256 * sizeof(u16);   // 25.6 MB
    u16* Glo  = (u16*)ws;    ws += (size_t)n * 256 * sizeof(u16);   // 25.6 MB
    u16* Hb3  = (u16*)ws;    ws += (size_t)n * 32 * sizeof(u16);    // 3.2 MB
    u16* B2h  = (u16*)ws;    ws += (size_t)8 * 16 * 64 * 8 * sizeof(u16);  // 128 KB
    u16* B3h  = (u16*)ws;    ws += (size_t)8 * 2 * 64 * 8 * sizeof(u16);   // 16 KB
    float* U2 = (float*)ws;  ws += (size_t)8 * 256 * sizeof(float);
    float* U3 = (float*)ws;  ws += (size_t)2 * 256 * sizeof(float);
    float* sAs = (float*)ws; ws += (size_t)n * 4 * sizeof(float);
    float* sAd = (float*)ws; ws += (size_t)n * 4 * sizeof(float);
    float* sBs = (float*)ws; ws += (size_t)n * 4 * sizeof(float);
    float* sBd = (float*)ws; ws += (size_t)n * 4 * sizeof(float);
    float* sCs = (float*)ws; ws += (size_t)n * sizeof(float);
    float* sCd = (float*)ws; ws += (size_t)n * sizeof(float);
    int* deg    = (int*)ws;  ws += (size_t)n * sizeof(int);
    int* offs   = (int*)ws;  ws += (size_t)(n + 1) * sizeof(int) + 12;
    int* cursor = (int*)ws;  ws += (size_t)n * sizeof(int);
    int* partial = (int*)ws; ws += (size_t)128 * sizeof(int);
    int* csr    = (int*)ws;  ws += (size_t)Etot * sizeof(int);   // keep csr LAST

    // ---- CSR build (by dst) ----
    hipMemsetAsync(deg, 0, (size_t)n * sizeof(int), stream);
    int eblocks = (Etot + 255) / 256;
    edge_count<<<eblocks, 256, 0, stream>>>(ei, E, n, deg);
    int sb = (n + 1023) / 1024;
    scan_partials<<<sb, 256, 0, stream>>>(deg, partial, n);
    scan_mid<<<1, 128, 0, stream>>>(partial, sb, offs, n);
    scan_final<<<sb, 256, 0, stream>>>(deg, partial, offs, cursor, n);
    edge_fill<<<eblocks, 256, 0, stream>>>(ei, E, n, cursor, csr);

    // ---- Weight prep ----
    pack_hi<<<(8 * 16 * 64 + 255) / 256, 256, 0, stream>>>(W2, B2h, 256);
    pack_hi<<<(8 * 2 * 64 + 255) / 256, 256, 0, stream>>>(W3, B3h, 32);
    make_u<<<4, 64, 0, stream>>>(W2, as2, ad2, U2, 64, 4);
    make_u<<<4, 64, 0, stream>>>(W3, as3, ad3, U3, 32, 1);

    int nb4 = (n + 3) / 4;
    int nb64 = (n + 63) / 64;

    // ---- Layer 1: 3 -> (4 x 64), concat, relu ----
    linear1<<<n, 256, 0, stream>>>(x, W1, as1, ad1, Hb, sAs, sAd, n);
    gat_aggregate_m4<8><<<nb4, 256, 0, stream>>>(Hb, sAs, sAd, offs, csr, b1, U2,
                                                 Ghi, Glo, sBs, sBd, n);

    // ---- Layer 2: 256 -> (4 x 64), concat, relu ----
    gemm_lds<16><<<nb64, 256, 0, stream>>>(Ghi, Glo, B2h, Hb, n);
    gat_aggregate_m4<2><<<nb4, 256, 0, stream>>>(Hb, sBs, sBd, offs, csr, b2, U3,
                                                 Ghi, Glo, sCs, sCd, n);

    // ---- Layer 3: 256 -> (1 x 32), mean(=identity), no relu ----
    gemm_lds<2><<<nb64, 256, 0, stream>>>(Ghi, Glo, B3h, Hb3, n);
    gat_aggregate_h1<<<nb4, 256, 0, stream>>>(Hb3, sCs, sCd, offs, csr, b3, out, n);
}

// Round 11
// 399.080 us; speedup vs baseline: 1.0020x; 1.0020x over previous
//
#include <hip/hip_runtime.h>
#include <math.h>

// =====================================================================
// 3-layer GAT (PyG GATConv) on MI355X.
// R11: identical to R10 except gemm_lds gets __launch_bounds__(256, 1).
// R9/R10's GEMM regression was the register allocator spilling the
// B-prefetch array st[] to scratch (~72 MB/dispatch of private-memory
// round-trips; WRITE_SIZE 97.6 MB vs 26.5 logical) to chase a high
// default occupancy target. (256,1) unlocks the VGPR budget.
// Values flow bf16; logits fp32-exact end-to-end.
// =====================================================================

#define NEG_SLOPE 0.2f

typedef unsigned short u16;
typedef short bf16x8 __attribute__((ext_vector_type(8)));
typedef float floatx4 __attribute__((ext_vector_type(4)));

__device__ __forceinline__ float b2f(u16 u) {
    return __uint_as_float(((unsigned int)u) << 16);
}
__device__ __forceinline__ u16 f2b(float f) {
    unsigned int u = __float_as_uint(f);
    unsigned int r = (u + 0x7fffu + ((u >> 16) & 1u)) >> 16;   // RNE
    return (u16)r;
}

// ---------------- CSR build ----------------

__global__ __launch_bounds__(256) void edge_count(const int* __restrict__ ei, int E, int n,
                                                  int* __restrict__ deg) {
    int e = blockIdx.x * blockDim.x + threadIdx.x;
    int Etot = E + n;
    if (e >= Etot) return;
    int dst = (e < E) ? ei[E + e] : (e - E);   // self-loop for e >= E
    atomicAdd(&deg[dst], 1);
}

__global__ __launch_bounds__(256) void scan_partials(const int* __restrict__ deg,
                                                     int* __restrict__ partial, int n) {
    __shared__ int red[256];
    int i0 = blockIdx.x * 1024 + threadIdx.x * 4;
    int s = 0;
#pragma unroll
    for (int r = 0; r < 4; ++r) s += (i0 + r < n) ? deg[i0 + r] : 0;
    red[threadIdx.x] = s;
    __syncthreads();
    for (int off = 128; off > 0; off >>= 1) {
        if (threadIdx.x < off) red[threadIdx.x] += red[threadIdx.x + off];
        __syncthreads();
    }
    if (threadIdx.x == 0) partial[blockIdx.x] = red[0];
}

__global__ __launch_bounds__(128) void scan_mid(int* __restrict__ partial, int nb,
                                                int* __restrict__ offs, int n) {
    __shared__ int s[128];
    int v = (threadIdx.x < nb) ? partial[threadIdx.x] : 0;
    s[threadIdx.x] = v;
    __syncthreads();
    for (int off = 1; off < 128; off <<= 1) {
        int t = (threadIdx.x >= off) ? s[threadIdx.x - off] : 0;
        __syncthreads();
        s[threadIdx.x] += t;
        __syncthreads();
    }
    if (threadIdx.x < nb) partial[threadIdx.x] = s[threadIdx.x] - v;   // exclusive
    if (threadIdx.x == nb - 1) offs[n] = s[threadIdx.x];               // total
}

__global__ __launch_bounds__(256) void scan_final(const int* __restrict__ deg,
                                                  const int* __restrict__ partial,
                                                  int* __restrict__ offs,
                                                  int* __restrict__ cursor, int n) {
    __shared__ int s[256];
    int i0 = blockIdx.x * 1024 + threadIdx.x * 4;
    int v[4];
    int sum = 0;
#pragma unroll
    for (int r = 0; r < 4; ++r) {
        v[r] = (i0 + r < n) ? deg[i0 + r] : 0;
        sum += v[r];
    }
    s[threadIdx.x] = sum;
    __syncthreads();
    for (int off = 1; off < 256; off <<= 1) {
        int t = (threadIdx.x >= off) ? s[threadIdx.x - off] : 0;
        __syncthreads();
        s[threadIdx.x] += t;
        __syncthreads();
    }
    int excl = s[threadIdx.x] - sum + partial[blockIdx.x];
#pragma unroll
    for (int r = 0; r < 4; ++r) {
        if (i0 + r < n) { offs[i0 + r] = excl; cursor[i0 + r] = excl; }
        excl += v[r];
    }
}

__global__ __launch_bounds__(256) void edge_fill(const int* __restrict__ ei, int E, int n,
                                                 int* __restrict__ cursor,
                                                 int* __restrict__ csr) {
    int e = blockIdx.x * blockDim.x + threadIdx.x;
    int Etot = E + n;
    if (e >= Etot) return;
    int src, dst;
    if (e < E) { src = ei[e]; dst = ei[E + e]; }
    else       { src = e - E; dst = e - E; }
    int pos = atomicAdd(&cursor[dst], 1);
    csr[pos] = src;
}

// -------- Pack W (hi bf16 only) into MFMA-fragment-major layout ----------
// Unit u = kb*CT*64 + ct*64 + lane holds 8 bf16: W[kb*32+(lane>>4)*8+j][ct*16+(lane&15)].

__global__ __launch_bounds__(256) void pack_hi(const float* __restrict__ W,
                                               u16* __restrict__ Bh, int N) {
    int CT = N / 16;
    int idx = blockIdx.x * blockDim.x + threadIdx.x;
    if (idx >= 8 * CT * 64) return;
    int lane = idx & 63;
    int ctkb = idx >> 6;
    int ct = ctkb % CT;
    int kb = ctkb / CT;
    int col = ct * 16 + (lane & 15);
    int k0 = kb * 32 + (lane >> 4) * 8;
#pragma unroll
    for (int j = 0; j < 8; ++j)
        Bh[(size_t)idx * 8 + j] = f2b(W[(size_t)(k0 + j) * N + col]);
}

// -------- U = W·a (per-head score vectors in input space), fp32 exact ----
// U[v][k], v in [0,HEADS) = src heads, [HEADS,2*HEADS) = dst heads.

__global__ __launch_bounds__(64) void make_u(const float* __restrict__ W,
                                             const float* __restrict__ as,
                                             const float* __restrict__ ad,
                                             float* __restrict__ U, int C, int HEADS) {
    int k = blockIdx.x * 64 + threadIdx.x;
    if (k >= 256) return;
    const float* wr = W + (size_t)k * (HEADS * C);
    for (int h = 0; h < HEADS; ++h) {
        float s = 0.f, d = 0.f;
        for (int c = 0; c < C; ++c) {
            float wv = wr[h * C + c];
            s = fmaf(wv, as[h * C + c], s);
            d = fmaf(wv, ad[h * C + c], d);
        }
        U[h * 256 + k] = s;
        U[(HEADS + h) * 256 + k] = d;
    }
}

// ------- Layer-1 linear (K=3) + fused scores; writes bf16 shadow ---------

__global__ __launch_bounds__(256) void linear1(const float* __restrict__ x,
                                               const float* __restrict__ W,
                                               const float* __restrict__ asrc,
                                               const float* __restrict__ adst,
                                               u16* __restrict__ Hb,
                                               float* __restrict__ ssrc,
                                               float* __restrict__ sdst, int n) {
    int node = blockIdx.x;
    if (node >= n) return;
    int c = threadIdx.x;
    int head = c >> 6, lane = c & 63;
    float x0 = x[node * 3 + 0], x1 = x[node * 3 + 1], x2 = x[node * 3 + 2];
    float v = fmaf(x0, W[c], fmaf(x1, W[256 + c], x2 * W[512 + c]));
    Hb[(size_t)node * 256 + c] = f2b(v);
    float va = v * asrc[c];
    float vb = v * adst[c];
#pragma unroll
    for (int o = 32; o > 0; o >>= 1) {
        va += __shfl_xor(va, o);
        vb += __shfl_xor(vb, o);
    }
    if (lane == 0) { ssrc[node * 4 + head] = va; sdst[node * 4 + head] = vb; }
}

// ------- Lean MFMA GEMM: Hb = bf16( (Ahi+Alo) · Whi^T ) ------------------
// A pre-split hi/lo bf16 planes [n][256]; B fragment-major bf16.
// Double-buffered LDS B staging with register prefetch; one barrier/k-step.
// __launch_bounds__(256, 1): allow full VGPR budget so the prefetch array
// st[] stays in registers (default occupancy target spilled it to scratch:
// R9/R10's 97-103 MB WRITE_SIZE).
// Fragments: A[m=lane&15][k=(lane>>4)*8+j]; D reg r -> row (l>>4)*4+r, col l&15.

template <int CT>
__global__ __launch_bounds__(256, 1) void gemm_lds(const u16* __restrict__ Ahi,
                                                   const u16* __restrict__ Alo,
                                                   const u16* __restrict__ Bh,
                                                   u16* __restrict__ Hb, int n) {
    constexpr int UN = CT * 64;                 // 16-byte units per k-slice
    constexpr int SU = (UN + 255) / 256;        // units per thread (static)
    __shared__ __align__(16) u16 sB[2][UN * 8];
    int t = threadIdx.x;
    int w = t >> 6, l = t & 63;
    int m0 = blockIdx.x * 64 + w * 16;
    int lm = l & 15, q = l >> 4;
    floatx4 acc[CT] = {};
    int arow = min(m0 + lm, n - 1);
    const u16* ahp = Ahi + (size_t)arow * 256 + q * 8;
    const u16* alp = Alo + (size_t)arow * 256 + q * 8;

    // prologue: stage slice 0, load A frag 0
#pragma unroll
    for (int i = 0; i < SU; ++i) {
        int u = t + i * 256;
        if (u < UN) *(uint4*)&sB[0][u * 8] = *(const uint4*)&Bh[(size_t)u * 8];
    }
    bf16x8 ahi = *(const bf16x8*)(ahp);
    bf16x8 alo = *(const bf16x8*)(alp);
    __syncthreads();

    for (int kb = 0; kb < 8; ++kb) {
        int cur = kb & 1;
        uint4 st[SU];
        bf16x8 nahi = ahi, nalo = alo;
        if (kb < 7) {                     // prefetch next B slice + next A frag
#pragma unroll
            for (int i = 0; i < SU; ++i) {
                int u = t + i * 256;
                if (u < UN)
                    st[i] = *(const uint4*)&Bh[((size_t)(kb + 1) * UN + u) * 8];
            }
            nahi = *(const bf16x8*)(ahp + (kb + 1) * 32);
            nalo = *(const bf16x8*)(alp + (kb + 1) * 32);
        }
#pragma unroll
        for (int ct = 0; ct < CT; ++ct) {
            bf16x8 bhi = *(const bf16x8*)&sB[cur][(ct * 64 + l) * 8];
            acc[ct] = __builtin_amdgcn_mfma_f32_16x16x32_bf16(ahi, bhi, acc[ct], 0, 0, 0);
            acc[ct] = __builtin_amdgcn_mfma_f32_16x16x32_bf16(alo, bhi, acc[ct], 0, 0, 0);
        }
        if (kb < 7) {
#pragma unroll
            for (int i = 0; i < SU; ++i) {
                int u = t + i * 256;
                if (u < UN) *(uint4*)&sB[cur ^ 1][u * 8] = st[i];
            }
            ahi = nahi; alo = nalo;
        }
        __syncthreads();
    }
#pragma unroll
    for (int ct = 0; ct < CT; ++ct)
#pragma unroll
        for (int r = 0; r < 4; ++r) {
            int row = m0 + q * 4 + r;
            if (row < n)
                Hb[(size_t)row * (CT * 16) + ct * 16 + lm] = f2b(acc[ct][r]);
        }
}

// ---------------- Merged 4-head aggregation (layers 1 & 2) ----------------
// One wave per dst node; bf16 value gathers, fp32 logits/accum.
// Epilogue: writes hi/lo bf16 planes of the relu'd output AND next-layer
// scores p[v] = g·U[v] (fp32-exact), NU = 2*heads_next.

template <int NU>
__global__ __launch_bounds__(256) void gat_aggregate_m4(const u16* __restrict__ Hb,
                                                        const float* __restrict__ ssrc,
                                                        const float* __restrict__ sdst,
                                                        const int* __restrict__ offs,
                                                        const int* __restrict__ csr,
                                                        const float* __restrict__ bias,
                                                        const float* __restrict__ U,
                                                        u16* __restrict__ Ghi,
                                                        u16* __restrict__ Glo,
                                                        float* __restrict__ sOs,
                                                        float* __restrict__ sOd, int n) {
    int node = blockIdx.x * 4 + (threadIdx.x >> 6);
    int lane = threadIdx.x & 63;
    if (node >= n) return;
    const int hB = lane & 3;
    const int eL = lane >> 2;
    const int hA = lane >> 4;
    int beg = offs[node], end = offs[node + 1];
    float sd = sdst[node * 4 + hB];
    float m = -INFINITY, l = 0.f;
    float4 acc = make_float4(0.f, 0.f, 0.f, 0.f);

    for (int base = beg; base < end; base += 16) {
        int j = base + eL;
        bool valid = (j < end);
        int sj = valid ? csr[j] : 0;
        float logit = -INFINITY;
        if (valid) {
            float xv = ssrc[sj * 4 + hB] + sd;
            logit = (xv > 0.f) ? xv : NEG_SLOPE * xv;
        }
        float cm = logit;
        cm = fmaxf(cm, __shfl_xor(cm, 4));
        cm = fmaxf(cm, __shfl_xor(cm, 8));
        cm = fmaxf(cm, __shfl_xor(cm, 16));
        cm = fmaxf(cm, __shfl_xor(cm, 32));
        float nm = fmaxf(m, cm);
        float scale = __expf(m - nm);       // m=-inf -> 0
        float ex = valid ? __expf(logit - nm) : 0.f;
        float es = ex;
        es += __shfl_xor(es, 4);
        es += __shfl_xor(es, 8);
        es += __shfl_xor(es, 16);
        es += __shfl_xor(es, 32);
        l = l * scale + es;
        m = nm;
        float sA = __shfl(scale, hA);
        acc.x *= sA; acc.y *= sA; acc.z *= sA; acc.w *= sA;

        int cnt = min(16, end - base);
        for (int t = 0; t < cnt; t += 4) {
#pragma unroll
            for (int u = 0; u < 4; ++u) {
                int tt = t + u;
                float a = __shfl(ex, tt * 4 + hA);   // 0 for invalid edges
                int s = __shfl(sj, tt * 4);          // 0 for invalid (safe addr)
                ushort4 hv = *(const ushort4*)&Hb[(size_t)s * 256 + lane * 4];
                acc.x = fmaf(a, b2f(hv.x), acc.x);
                acc.y = fmaf(a, b2f(hv.y), acc.y);
                acc.z = fmaf(a, b2f(hv.z), acc.z);
                acc.w = fmaf(a, b2f(hv.w), acc.w);
            }
        }
    }
    float lf = __shfl(l, hA);
    float inv = 1.f / lf;
    const float4 bv = *(const float4*)&bias[lane * 4];
    float4 o;
    o.x = fmaxf(fmaf(acc.x, inv, bv.x), 0.f);   // relu
    o.y = fmaxf(fmaf(acc.y, inv, bv.y), 0.f);
    o.z = fmaxf(fmaf(acc.z, inv, bv.z), 0.f);
    o.w = fmaxf(fmaf(acc.w, inv, bv.w), 0.f);
    // hi/lo bf16 planes (fp32-equivalent for the next GEMM)
    ushort4 h4, l4;
    h4.x = f2b(o.x); l4.x = f2b(o.x - b2f(h4.x));
    h4.y = f2b(o.y); l4.y = f2b(o.y - b2f(h4.y));
    h4.z = f2b(o.z); l4.z = f2b(o.z - b2f(h4.z));
    h4.w = f2b(o.w); l4.w = f2b(o.w - b2f(h4.w));
    *(ushort4*)&Ghi[(size_t)node * 256 + lane * 4] = h4;
    *(ushort4*)&Glo[(size_t)node * 256 + lane * 4] = l4;
    // next-layer scores: p[v] = g · U[v]   (fp32-exact logit path)
    float p[NU];
#pragma unroll
    for (int v = 0; v < NU; ++v) {
        const float4 uv = *(const float4*)&U[v * 256 + lane * 4];
        p[v] = o.x * uv.x + o.y * uv.y + o.z * uv.z + o.w * uv.w;
#pragma unroll
        for (int s = 32; s > 0; s >>= 1) p[v] += __shfl_xor(p[v], s);
    }
#pragma unroll
    for (int v = 0; v < NU; ++v) {
        if (lane == v) {
            if (v < NU / 2) sOs[node * (NU / 2) + v] = p[v];
            else            sOd[node * (NU / 2) + (v - NU / 2)] = p[v];
        }
    }
}

// ---------------- Single-head aggregation (layer 3, C=32, no relu) --------

__global__ __launch_bounds__(256) void gat_aggregate_h1(const u16* __restrict__ Hb,
                                                        const float* __restrict__ ssrc,
                                                        const float* __restrict__ sdst,
                                                        const int* __restrict__ offs,
                                                        const int* __restrict__ csr,
                                                        const float* __restrict__ bias,
                                                        float* __restrict__ out, int n) {
    int node = blockIdx.x * 4 + (threadIdx.x >> 6);
    int lane = threadIdx.x & 63;
    if (node >= n) return;
    int beg = offs[node], end = offs[node + 1];
    float sd = sdst[node];
    float m = -INFINITY, l = 0.f, acc = 0.f;

    for (int base = beg; base < end; base += 64) {
        int j = base + lane;
        bool valid = (j < end);
        int sj = valid ? csr[j] : 0;
        float logit = -INFINITY;
        if (valid) {
            float xv = ssrc[sj] + sd;
            logit = (xv > 0.f) ? xv : NEG_SLOPE * xv;
        }
        float cm = logit;
#pragma unroll
        for (int o = 32; o > 0; o >>= 1) cm = fmaxf(cm, __shfl_xor(cm, o));
        float nm = fmaxf(m, cm);
        float scale = __expf(m - nm);
        float ex = valid ? __expf(logit - nm) : 0.f;
        float es = ex;
#pragma unroll
        for (int o = 32; o > 0; o >>= 1) es += __shfl_xor(es, o);
        l = l * scale + es;
        m = nm;
        acc *= scale;
        int cnt = min(64, end - base);
        for (int t = 0; t < cnt; t += 4) {
#pragma unroll
            for (int u = 0; u < 4; ++u) {
                float a = __shfl(ex, t + u);
                int s = __shfl(sj, t + u);
                if (lane < 32) acc = fmaf(a, b2f(Hb[(size_t)s * 32 + lane]), acc);
            }
        }
    }
    if (lane < 32) out[(size_t)node * 32 + lane] = acc / l + bias[lane];
}

// ---------------- Launch ----------------

extern "C" void kernel_launch(void* const* d_in, const int* in_sizes, int n_in,
                              void* d_out, int out_size, void* d_ws, size_t ws_size,
                              hipStream_t stream) {
    const float* x   = (const float*)d_in[0];
    const int*   ei  = (const int*)d_in[1];
    const float* W1  = (const float*)d_in[2];
    const float* as1 = (const float*)d_in[3];
    const float* ad1 = (const float*)d_in[4];
    const float* b1  = (const float*)d_in[5];
    const float* W2  = (const float*)d_in[6];
    const float* as2 = (const float*)d_in[7];
    const float* ad2 = (const float*)d_in[8];
    const float* b2  = (const float*)d_in[9];
    const float* W3  = (const float*)d_in[10];
    const float* as3 = (const float*)d_in[11];
    const float* ad3 = (const float*)d_in[12];
    const float* b3  = (const float*)d_in[13];
    float* out = (float*)d_out;

    const int n = in_sizes[0] / 3;     // 50000
    const int E = in_sizes[1] / 2;     // 400000
    const int Etot = E + n;            // with self-loops

    // workspace layout
    char* ws = (char*)d_ws;
    u16* Hb   = (u16*)ws;    ws += (size_t)n * 256 * sizeof(u16);   // 25.6 MB shadow
    u16* Ghi  = (u16*)ws;    ws += (size_t)n * 256 * sizeof(u16);   // 25.6 MB
    u16* Glo  = (u16*)ws;    ws += (size_t)n * 256 * sizeof(u16);   // 25.6 MB
    u16* Hb3  = (u16*)ws;    ws += (size_t)n * 32 * sizeof(u16);    // 3.2 MB
    u16* B2h  = (u16*)ws;    ws += (size_t)8 * 16 * 64 * 8 * sizeof(u16);  // 128 KB
    u16* B3h  = (u16*)ws;    ws += (size_t)8 * 2 * 64 * 8 * sizeof(u16);   // 16 KB
    float* U2 = (float*)ws;  ws += (size_t)8 * 256 * sizeof(float);
    float* U3 = (float*)ws;  ws += (size_t)2 * 256 * sizeof(float);
    float* sAs = (float*)ws; ws += (size_t)n * 4 * sizeof(float);
    float* sAd = (float*)ws; ws += (size_t)n * 4 * sizeof(float);
    float* sBs = (float*)ws; ws += (size_t)n * 4 * sizeof(float);
    float* sBd = (float*)ws; ws += (size_t)n * 4 * sizeof(float);
    float* sCs = (float*)ws; ws += (size_t)n * sizeof(float);
    float* sCd = (float*)ws; ws += (size_t)n * sizeof(float);
    int* deg    = (int*)ws;  ws += (size_t)n * sizeof(int);
    int* offs   = (int*)ws;  ws += (size_t)(n + 1) * sizeof(int) + 12;
    int* cursor = (int*)ws;  ws += (size_t)n * sizeof(int);
    int* partial = (int*)ws; ws += (size_t)128 * sizeof(int);
    int* csr    = (int*)ws;  ws += (size_t)Etot * sizeof(int);   // keep csr LAST

    // ---- CSR build (by dst) ----
    hipMemsetAsync(deg, 0, (size_t)n * sizeof(int), stream);
    int eblocks = (Etot + 255) / 256;
    edge_count<<<eblocks, 256, 0, stream>>>(ei, E, n, deg);
    int sb = (n + 1023) / 1024;
    scan_partials<<<sb, 256, 0, stream>>>(deg, partial, n);
    scan_mid<<<1, 128, 0, stream>>>(partial, sb, offs, n);
    scan_final<<<sb, 256, 0, stream>>>(deg, partial, offs, cursor, n);
    edge_fill<<<eblocks, 256, 0, stream>>>(ei, E, n, cursor, csr);

    // ---- Weight prep ----
    pack_hi<<<(8 * 16 * 64 + 255) / 256, 256, 0, stream>>>(W2, B2h, 256);
    pack_hi<<<(8 * 2 * 64 + 255) / 256, 256, 0, stream>>>(W3, B3h, 32);
    make_u<<<4, 64, 0, stream>>>(W2, as2, ad2, U2, 64, 4);
    make_u<<<4, 64, 0, stream>>>(W3, as3, ad3, U3, 32, 1);

    int nb4 = (n + 3) / 4;
    int nb64 = (n + 63) / 64;

    // ---- Layer 1: 3 -> (4 x 64), concat, relu ----
    linear1<<<n, 256, 0, stream>>>(x, W1, as1, ad1, Hb, sAs, sAd, n);
    gat_aggregate_m4<8><<<nb4, 256, 0, stream>>>(Hb, sAs, sAd, offs, csr, b1, U2,
                                                 Ghi, Glo, sBs, sBd, n);

    // ---- Layer 2: 256 -> (4 x 64), concat, relu ----
    gemm_lds<16><<<nb64, 256, 0, stream>>>(Ghi, Glo, B2h, Hb, n);
    gat_aggregate_m4<2><<<nb4, 256, 0, stream>>>(Hb, sBs, sBd, offs, csr, b2, U3,
                                                 Ghi, Glo, sCs, sCd, n);

    // ---- Layer 3: 256 -> (1 x 32), mean(=identity), no relu ----
    gemm_lds<2><<<nb64, 256, 0, stream>>>(Ghi, Glo, B3h, Hb3, n);
    gat_aggregate_h1<<<nb4, 256, 0, stream>>>(Hb3, sCs, sCd, offs, csr, b3, out, n);
}

// Round 12
// 379.653 us; speedup vs baseline: 1.0533x; 1.0512x over previous
//
#include <hip/hip_runtime.h>
#include <math.h>

// =====================================================================
// 3-layer GAT (PyG GATConv) on MI355X.
// R12: R9's lean math (U=W·a fused scores in aggregates, hi/lo bf16
// planes, 2-MFMA inner loop) transplanted into R8's proven GEMM staging
// skeleton (direct global->LDS loop, single buffer, no register
// prefetch array). R9-R11's st[] prefetch array was compiler-spilled to
// scratch (~71 MB/dispatch writeback) regardless of launch_bounds.
// Values flow bf16; logits fp32-exact end-to-end.
// =====================================================================

#define NEG_SLOPE 0.2f

typedef unsigned short u16;
typedef short bf16x8 __attribute__((ext_vector_type(8)));
typedef float floatx4 __attribute__((ext_vector_type(4)));

__device__ __forceinline__ float b2f(u16 u) {
    return __uint_as_float(((unsigned int)u) << 16);
}
__device__ __forceinline__ u16 f2b(float f) {
    unsigned int u = __float_as_uint(f);
    unsigned int r = (u + 0x7fffu + ((u >> 16) & 1u)) >> 16;   // RNE
    return (u16)r;
}

// ---------------- CSR build ----------------

__global__ __launch_bounds__(256) void edge_count(const int* __restrict__ ei, int E, int n,
                                                  int* __restrict__ deg) {
    int e = blockIdx.x * blockDim.x + threadIdx.x;
    int Etot = E + n;
    if (e >= Etot) return;
    int dst = (e < E) ? ei[E + e] : (e - E);   // self-loop for e >= E
    atomicAdd(&deg[dst], 1);
}

__global__ __launch_bounds__(256) void scan_partials(const int* __restrict__ deg,
                                                     int* __restrict__ partial, int n) {
    __shared__ int red[256];
    int i0 = blockIdx.x * 1024 + threadIdx.x * 4;
    int s = 0;
#pragma unroll
    for (int r = 0; r < 4; ++r) s += (i0 + r < n) ? deg[i0 + r] : 0;
    red[threadIdx.x] = s;
    __syncthreads();
    for (int off = 128; off > 0; off >>= 1) {
        if (threadIdx.x < off) red[threadIdx.x] += red[threadIdx.x + off];
        __syncthreads();
    }
    if (threadIdx.x == 0) partial[blockIdx.x] = red[0];
}

__global__ __launch_bounds__(128) void scan_mid(int* __restrict__ partial, int nb,
                                                int* __restrict__ offs, int n) {
    __shared__ int s[128];
    int v = (threadIdx.x < nb) ? partial[threadIdx.x] : 0;
    s[threadIdx.x] = v;
    __syncthreads();
    for (int off = 1; off < 128; off <<= 1) {
        int t = (threadIdx.x >= off) ? s[threadIdx.x - off] : 0;
        __syncthreads();
        s[threadIdx.x] += t;
        __syncthreads();
    }
    if (threadIdx.x < nb) partial[threadIdx.x] = s[threadIdx.x] - v;   // exclusive
    if (threadIdx.x == nb - 1) offs[n] = s[threadIdx.x];               // total
}

__global__ __launch_bounds__(256) void scan_final(const int* __restrict__ deg,
                                                  const int* __restrict__ partial,
                                                  int* __restrict__ offs,
                                                  int* __restrict__ cursor, int n) {
    __shared__ int s[256];
    int i0 = blockIdx.x * 1024 + threadIdx.x * 4;
    int v[4];
    int sum = 0;
#pragma unroll
    for (int r = 0; r < 4; ++r) {
        v[r] = (i0 + r < n) ? deg[i0 + r] : 0;
        sum += v[r];
    }
    s[threadIdx.x] = sum;
    __syncthreads();
    for (int off = 1; off < 256; off <<= 1) {
        int t = (threadIdx.x >= off) ? s[threadIdx.x - off] : 0;
        __syncthreads();
        s[threadIdx.x] += t;
        __syncthreads();
    }
    int excl = s[threadIdx.x] - sum + partial[blockIdx.x];
#pragma unroll
    for (int r = 0; r < 4; ++r) {
        if (i0 + r < n) { offs[i0 + r] = excl; cursor[i0 + r] = excl; }
        excl += v[r];
    }
}

__global__ __launch_bounds__(256) void edge_fill(const int* __restrict__ ei, int E, int n,
                                                 int* __restrict__ cursor,
                                                 int* __restrict__ csr) {
    int e = blockIdx.x * blockDim.x + threadIdx.x;
    int Etot = E + n;
    if (e >= Etot) return;
    int src, dst;
    if (e < E) { src = ei[e]; dst = ei[E + e]; }
    else       { src = e - E; dst = e - E; }
    int pos = atomicAdd(&cursor[dst], 1);
    csr[pos] = src;
}

// -------- Pack W (hi bf16 only) into MFMA-fragment-major layout ----------
// Unit u = kb*CT*64 + ct*64 + lane holds 8 bf16: W[kb*32+(lane>>4)*8+j][ct*16+(lane&15)].

__global__ __launch_bounds__(256) void pack_hi(const float* __restrict__ W,
                                               u16* __restrict__ Bh, int N) {
    int CT = N / 16;
    int idx = blockIdx.x * blockDim.x + threadIdx.x;
    if (idx >= 8 * CT * 64) return;
    int lane = idx & 63;
    int ctkb = idx >> 6;
    int ct = ctkb % CT;
    int kb = ctkb / CT;
    int col = ct * 16 + (lane & 15);
    int k0 = kb * 32 + (lane >> 4) * 8;
#pragma unroll
    for (int j = 0; j < 8; ++j)
        Bh[(size_t)idx * 8 + j] = f2b(W[(size_t)(k0 + j) * N + col]);
}

// -------- U = W·a (per-head score vectors in input space), fp32 exact ----
// U[v][k], v in [0,HEADS) = src heads, [HEADS,2*HEADS) = dst heads.

__global__ __launch_bounds__(64) void make_u(const float* __restrict__ W,
                                             const float* __restrict__ as,
                                             const float* __restrict__ ad,
                                             float* __restrict__ U, int C, int HEADS) {
    int k = blockIdx.x * 64 + threadIdx.x;
    if (k >= 256) return;
    const float* wr = W + (size_t)k * (HEADS * C);
    for (int h = 0; h < HEADS; ++h) {
        float s = 0.f, d = 0.f;
        for (int c = 0; c < C; ++c) {
            float wv = wr[h * C + c];
            s = fmaf(wv, as[h * C + c], s);
            d = fmaf(wv, ad[h * C + c], d);
        }
        U[h * 256 + k] = s;
        U[(HEADS + h) * 256 + k] = d;
    }
}

// ------- Layer-1 linear (K=3) + fused scores; writes bf16 shadow ---------

__global__ __launch_bounds__(256) void linear1(const float* __restrict__ x,
                                               const float* __restrict__ W,
                                               const float* __restrict__ asrc,
                                               const float* __restrict__ adst,
                                               u16* __restrict__ Hb,
                                               float* __restrict__ ssrc,
                                               float* __restrict__ sdst, int n) {
    int node = blockIdx.x;
    if (node >= n) return;
    int c = threadIdx.x;
    int head = c >> 6, lane = c & 63;
    float x0 = x[node * 3 + 0], x1 = x[node * 3 + 1], x2 = x[node * 3 + 2];
    float v = fmaf(x0, W[c], fmaf(x1, W[256 + c], x2 * W[512 + c]));
    Hb[(size_t)node * 256 + c] = f2b(v);
    float va = v * asrc[c];
    float vb = v * adst[c];
#pragma unroll
    for (int o = 32; o > 0; o >>= 1) {
        va += __shfl_xor(va, o);
        vb += __shfl_xor(vb, o);
    }
    if (lane == 0) { ssrc[node * 4 + head] = va; sdst[node * 4 + head] = vb; }
}

// ------- Lean MFMA GEMM: Hb = bf16( (Ahi+Alo) · Whi^T ) ------------------
// A pre-split hi/lo bf16 planes [n][256]; B fragment-major bf16, staged
// per k-slice into LDS with R8's direct load->store loop (no register
// staging array -> no scratch spill). 2 MFMA per ct.
// Fragments: A[m=lane&15][k=(lane>>4)*8+j]; D reg r -> row (l>>4)*4+r, col l&15.

template <int CT>
__global__ __launch_bounds__(256) void gemm_lds(const u16* __restrict__ Ahi,
                                                const u16* __restrict__ Alo,
                                                const u16* __restrict__ Bh,
                                                u16* __restrict__ Hb, int n) {
    constexpr int UN = CT * 64;                 // 16-byte units per k-slice
    __shared__ __align__(16) u16 sB[UN * 8];
    int t = threadIdx.x;
    int w = t >> 6, l = t & 63;
    int m0 = blockIdx.x * 64 + w * 16;
    int lm = l & 15, q = l >> 4;
    floatx4 acc[CT] = {};
    int arow = min(m0 + lm, n - 1);
    const u16* ahp = Ahi + (size_t)arow * 256 + q * 8;
    const u16* alp = Alo + (size_t)arow * 256 + q * 8;

    for (int kb = 0; kb < 8; ++kb) {
        __syncthreads();
        // stage B k-slice, coalesced, one value live at a time
        for (int u = t; u < UN; u += 256)
            *(uint4*)&sB[u * 8] = *(const uint4*)&Bh[((size_t)kb * UN + u) * 8];
        // A fragments (overlap staging)
        bf16x8 ahi = *(const bf16x8*)(ahp + kb * 32);
        bf16x8 alo = *(const bf16x8*)(alp + kb * 32);
        __syncthreads();
#pragma unroll
        for (int ct = 0; ct < CT; ++ct) {
            bf16x8 bhi = *(const bf16x8*)&sB[(ct * 64 + l) * 8];
            acc[ct] = __builtin_amdgcn_mfma_f32_16x16x32_bf16(ahi, bhi, acc[ct], 0, 0, 0);
            acc[ct] = __builtin_amdgcn_mfma_f32_16x16x32_bf16(alo, bhi, acc[ct], 0, 0, 0);
        }
    }
#pragma unroll
    for (int ct = 0; ct < CT; ++ct)
#pragma unroll
        for (int r = 0; r < 4; ++r) {
            int row = m0 + q * 4 + r;
            if (row < n)
                Hb[(size_t)row * (CT * 16) + ct * 16 + lm] = f2b(acc[ct][r]);
        }
}

// ---------------- Merged 4-head aggregation (layers 1 & 2) ----------------
// One wave per dst node; bf16 value gathers, fp32 logits/accum.
// Epilogue: writes hi/lo bf16 planes of the relu'd output AND next-layer
// scores p[v] = g·U[v] (fp32-exact), NU = 2*heads_next.

template <int NU>
__global__ __launch_bounds__(256) void gat_aggregate_m4(const u16* __restrict__ Hb,
                                                        const float* __restrict__ ssrc,
                                                        const float* __restrict__ sdst,
                                                        const int* __restrict__ offs,
                                                        const int* __restrict__ csr,
                                                        const float* __restrict__ bias,
                                                        const float* __restrict__ U,
                                                        u16* __restrict__ Ghi,
                                                        u16* __restrict__ Glo,
                                                        float* __restrict__ sOs,
                                                        float* __restrict__ sOd, int n) {
    int node = blockIdx.x * 4 + (threadIdx.x >> 6);
    int lane = threadIdx.x & 63;
    if (node >= n) return;
    const int hB = lane & 3;
    const int eL = lane >> 2;
    const int hA = lane >> 4;
    int beg = offs[node], end = offs[node + 1];
    float sd = sdst[node * 4 + hB];
    float m = -INFINITY, l = 0.f;
    float4 acc = make_float4(0.f, 0.f, 0.f, 0.f);

    for (int base = beg; base < end; base += 16) {
        int j = base + eL;
        bool valid = (j < end);
        int sj = valid ? csr[j] : 0;
        float logit = -INFINITY;
        if (valid) {
            float xv = ssrc[sj * 4 + hB] + sd;
            logit = (xv > 0.f) ? xv : NEG_SLOPE * xv;
        }
        float cm = logit;
        cm = fmaxf(cm, __shfl_xor(cm, 4));
        cm = fmaxf(cm, __shfl_xor(cm, 8));
        cm = fmaxf(cm, __shfl_xor(cm, 16));
        cm = fmaxf(cm, __shfl_xor(cm, 32));
        float nm = fmaxf(m, cm);
        float scale = __expf(m - nm);       // m=-inf -> 0
        float ex = valid ? __expf(logit - nm) : 0.f;
        float es = ex;
        es += __shfl_xor(es, 4);
        es += __shfl_xor(es, 8);
        es += __shfl_xor(es, 16);
        es += __shfl_xor(es, 32);
        l = l * scale + es;
        m = nm;
        float sA = __shfl(scale, hA);
        acc.x *= sA; acc.y *= sA; acc.z *= sA; acc.w *= sA;

        int cnt = min(16, end - base);
        for (int t = 0; t < cnt; t += 4) {
#pragma unroll
            for (int u = 0; u < 4; ++u) {
                int tt = t + u;
                float a = __shfl(ex, tt * 4 + hA);   // 0 for invalid edges
                int s = __shfl(sj, tt * 4);          // 0 for invalid (safe addr)
                ushort4 hv = *(const ushort4*)&Hb[(size_t)s * 256 + lane * 4];
                acc.x = fmaf(a, b2f(hv.x), acc.x);
                acc.y = fmaf(a, b2f(hv.y), acc.y);
                acc.z = fmaf(a, b2f(hv.z), acc.z);
                acc.w = fmaf(a, b2f(hv.w), acc.w);
            }
        }
    }
    float lf = __shfl(l, hA);
    float inv = 1.f / lf;
    const float4 bv = *(const float4*)&bias[lane * 4];
    float4 o;
    o.x = fmaxf(fmaf(acc.x, inv, bv.x), 0.f);   // relu
    o.y = fmaxf(fmaf(acc.y, inv, bv.y), 0.f);
    o.z = fmaxf(fmaf(acc.z, inv, bv.z), 0.f);
    o.w = fmaxf(fmaf(acc.w, inv, bv.w), 0.f);
    // hi/lo bf16 planes (fp32-equivalent for the next GEMM)
    ushort4 h4, l4;
    h4.x = f2b(o.x); l4.x = f2b(o.x - b2f(h4.x));
    h4.y = f2b(o.y); l4.y = f2b(o.y - b2f(h4.y));
    h4.z = f2b(o.z); l4.z = f2b(o.z - b2f(h4.z));
    h4.w = f2b(o.w); l4.w = f2b(o.w - b2f(h4.w));
    *(ushort4*)&Ghi[(size_t)node * 256 + lane * 4] = h4;
    *(ushort4*)&Glo[(size_t)node * 256 + lane * 4] = l4;
    // next-layer scores: p[v] = g · U[v]   (fp32-exact logit path)
    float p[NU];
#pragma unroll
    for (int v = 0; v < NU; ++v) {
        const float4 uv = *(const float4*)&U[v * 256 + lane * 4];
        p[v] = o.x * uv.x + o.y * uv.y + o.z * uv.z + o.w * uv.w;
#pragma unroll
        for (int s = 32; s > 0; s >>= 1) p[v] += __shfl_xor(p[v], s);
    }
#pragma unroll
    for (int v = 0; v < NU; ++v) {
        if (lane == v) {
            if (v < NU / 2) sOs[node * (NU / 2) + v] = p[v];
            else            sOd[node * (NU / 2) + (v - NU / 2)] = p[v];
        }
    }
}

// ---------------- Single-head aggregation (layer 3, C=32, no relu) --------

__global__ __launch_bounds__(256) void gat_aggregate_h1(const u16* __restrict__ Hb,
                                                        const float* __restrict__ ssrc,
                                                        const float* __restrict__ sdst,
                                                        const int* __restrict__ offs,
                                                        const int* __restrict__ csr,
                                                        const float* __restrict__ bias,
                                                        float* __restrict__ out, int n) {
    int node = blockIdx.x * 4 + (threadIdx.x >> 6);
    int lane = threadIdx.x & 63;
    if (node >= n) return;
    int beg = offs[node], end = offs[node + 1];
    float sd = sdst[node];
    float m = -INFINITY, l = 0.f, acc = 0.f;

    for (int base = beg; base < end; base += 64) {
        int j = base + lane;
        bool valid = (j < end);
        int sj = valid ? csr[j] : 0;
        float logit = -INFINITY;
        if (valid) {
            float xv = ssrc[sj] + sd;
            logit = (xv > 0.f) ? xv : NEG_SLOPE * xv;
        }
        float cm = logit;
#pragma unroll
        for (int o = 32; o > 0; o >>= 1) cm = fmaxf(cm, __shfl_xor(cm, o));
        float nm = fmaxf(m, cm);
        float scale = __expf(m - nm);
        float ex = valid ? __expf(logit - nm) : 0.f;
        float es = ex;
#pragma unroll
        for (int o = 32; o > 0; o >>= 1) es += __shfl_xor(es, o);
        l = l * scale + es;
        m = nm;
        acc *= scale;
        int cnt = min(64, end - base);
        for (int t = 0; t < cnt; t += 4) {
#pragma unroll
            for (int u = 0; u < 4; ++u) {
                float a = __shfl(ex, t + u);
                int s = __shfl(sj, t + u);
                if (lane < 32) acc = fmaf(a, b2f(Hb[(size_t)s * 32 + lane]), acc);
            }
        }
    }
    if (lane < 32) out[(size_t)node * 32 + lane] = acc / l + bias[lane];
}

// ---------------- Launch ----------------

extern "C" void kernel_launch(void* const* d_in, const int* in_sizes, int n_in,
                              void* d_out, int out_size, void* d_ws, size_t ws_size,
                              hipStream_t stream) {
    const float* x   = (const float*)d_in[0];
    const int*   ei  = (const int*)d_in[1];
    const float* W1  = (const float*)d_in[2];
    const float* as1 = (const float*)d_in[3];
    const float* ad1 = (const float*)d_in[4];
    const float* b1  = (const float*)d_in[5];
    const float* W2  = (const float*)d_in[6];
    const float* as2 = (const float*)d_in[7];
    const float* ad2 = (const float*)d_in[8];
    const float* b2  = (const float*)d_in[9];
    const float* W3  = (const float*)d_in[10];
    const float* as3 = (const float*)d_in[11];
    const float* ad3 = (const float*)d_in[12];
    const float* b3  = (const float*)d_in[13];
    float* out = (float*)d_out;

    const int n = in_sizes[0] / 3;     // 50000
    const int E = in_sizes[1] / 2;     // 400000
    const int Etot = E + n;            // with self-loops

    // workspace layout
    char* ws = (char*)d_ws;
    u16* Hb   = (u16*)ws;    ws += (size_t)n * 256 * sizeof(u16);   // 25.6 MB shadow
    u16* Ghi  = (u16*)ws;    ws += (size_t)n * 256 * sizeof(u16);   // 25.6 MB
    u16* Glo  = (u16*)ws;    ws += (size_t)n * 256 * sizeof(u16);   // 25.6 MB
    u16* Hb3  = (u16*)ws;    ws += (size_t)n * 32 * sizeof(u16);    // 3.2 MB
    u16* B2h  = (u16*)ws;    ws += (size_t)8 * 16 * 64 * 8 * sizeof(u16);  // 128 KB
    u16* B3h  = (u16*)ws;    ws += (size_t)8 * 2 * 64 * 8 * sizeof(u16);   // 16 KB
    float* U2 = (float*)ws;  ws += (size_t)8 * 256 * sizeof(float);
    float* U3 = (float*)ws;  ws += (size_t)2 * 256 * sizeof(float);
    float* sAs = (float*)ws; ws += (size_t)n * 4 * sizeof(float);
    float* sAd = (float*)ws; ws += (size_t)n * 4 * sizeof(float);
    float* sBs = (float*)ws; ws += (size_t)n * 4 * sizeof(float);
    float* sBd = (float*)ws; ws += (size_t)n * 4 * sizeof(float);
    float* sCs = (float*)ws; ws += (size_t)n * sizeof(float);
    float* sCd = (float*)ws; ws += (size_t)n * sizeof(float);
    int* deg    = (int*)ws;  ws += (size_t)n * sizeof(int);
    int* offs   = (int*)ws;  ws += (size_t)(n + 1) * sizeof(int) + 12;
    int* cursor = (int*)ws;  ws += (size_t)n * sizeof(int);
    int* partial = (int*)ws; ws += (size_t)128 * sizeof(int);
    int* csr    = (int*)ws;  ws += (size_t)Etot * sizeof(int);   // keep csr LAST

    // ---- CSR build (by dst) ----
    hipMemsetAsync(deg, 0, (size_t)n * sizeof(int), stream);
    int eblocks = (Etot + 255) / 256;
    edge_count<<<eblocks, 256, 0, stream>>>(ei, E, n, deg);
    int sb = (n + 1023) / 1024;
    scan_partials<<<sb, 256, 0, stream>>>(deg, partial, n);
    scan_mid<<<1, 128, 0, stream>>>(partial, sb, offs, n);
    scan_final<<<sb, 256, 0, stream>>>(deg, partial, offs, cursor, n);
    edge_fill<<<eblocks, 256, 0, stream>>>(ei, E, n, cursor, csr);

    // ---- Weight prep ----
    pack_hi<<<(8 * 16 * 64 + 255) / 256, 256, 0, stream>>>(W2, B2h, 256);
    pack_hi<<<(8 * 2 * 64 + 255) / 256, 256, 0, stream>>>(W3, B3h, 32);
    make_u<<<4, 64, 0, stream>>>(W2, as2, ad2, U2, 64, 4);
    make_u<<<4, 64, 0, stream>>>(W3, as3, ad3, U3, 32, 1);

    int nb4 = (n + 3) / 4;
    int nb64 = (n + 63) / 64;

    // ---- Layer 1: 3 -> (4 x 64), concat, relu ----
    linear1<<<n, 256, 0, stream>>>(x, W1, as1, ad1, Hb, sAs, sAd, n);
    gat_aggregate_m4<8><<<nb4, 256, 0, stream>>>(Hb, sAs, sAd, offs, csr, b1, U2,
                                                 Ghi, Glo, sBs, sBd, n);

    // ---- Layer 2: 256 -> (4 x 64), concat, relu ----
    gemm_lds<16><<<nb64, 256, 0, stream>>>(Ghi, Glo, B2h, Hb, n);
    gat_aggregate_m4<2><<<nb4, 256, 0, stream>>>(Hb, sBs, sBd, offs, csr, b2, U3,
                                                 Ghi, Glo, sCs, sCd, n);

    // ---- Layer 3: 256 -> (1 x 32), mean(=identity), no relu ----
    gemm_lds<2><<<nb64, 256, 0, stream>>>(Ghi, Glo, B3h, Hb3, n);
    gat_aggregate_h1<<<nb4, 256, 0, stream>>>(Hb3, sCs, sCd, offs, csr, b3, out, n);
}

// Round 13
// 378.335 us; speedup vs baseline: 1.0570x; 1.0035x over previous
//
#include <hip/hip_runtime.h>
#include <math.h>

// =====================================================================
// 3-layer GAT (PyG GATConv) on MI355X.
// R13: next-layer attention scores computed INSIDE the GEMM as an extra
// MFMA column-tile (B-columns = U = W·a, packed hi/lo bf16; score =
// ghi·Uhi + glo·Uhi + ghi·Ulo, fp32 acc, plain-store epilogue).
// Aggregates are slim (R8-style): gather bf16, fp32 softmax/accum,
// write hi/lo bf16 planes, no score epilogue.
// GEMM staging = R12's direct global->LDS loop (no spill).
// =====================================================================

#define NEG_SLOPE 0.2f

typedef unsigned short u16;
typedef short bf16x8 __attribute__((ext_vector_type(8)));
typedef float floatx4 __attribute__((ext_vector_type(4)));

__device__ __forceinline__ float b2f(u16 u) {
    return __uint_as_float(((unsigned int)u) << 16);
}
__device__ __forceinline__ u16 f2b(float f) {
    unsigned int u = __float_as_uint(f);
    unsigned int r = (u + 0x7fffu + ((u >> 16) & 1u)) >> 16;   // RNE
    return (u16)r;
}

// ---------------- CSR build ----------------

__global__ __launch_bounds__(256) void edge_count(const int* __restrict__ ei, int E, int n,
                                                  int* __restrict__ deg) {
    int e = blockIdx.x * blockDim.x + threadIdx.x;
    int Etot = E + n;
    if (e >= Etot) return;
    int dst = (e < E) ? ei[E + e] : (e - E);   // self-loop for e >= E
    atomicAdd(&deg[dst], 1);
}

__global__ __launch_bounds__(256) void scan_partials(const int* __restrict__ deg,
                                                     int* __restrict__ partial, int n) {
    __shared__ int red[256];
    int i0 = blockIdx.x * 1024 + threadIdx.x * 4;
    int s = 0;
#pragma unroll
    for (int r = 0; r < 4; ++r) s += (i0 + r < n) ? deg[i0 + r] : 0;
    red[threadIdx.x] = s;
    __syncthreads();
    for (int off = 128; off > 0; off >>= 1) {
        if (threadIdx.x < off) red[threadIdx.x] += red[threadIdx.x + off];
        __syncthreads();
    }
    if (threadIdx.x == 0) partial[blockIdx.x] = red[0];
}

__global__ __launch_bounds__(128) void scan_mid(int* __restrict__ partial, int nb,
                                                int* __restrict__ offs, int n) {
    __shared__ int s[128];
    int v = (threadIdx.x < nb) ? partial[threadIdx.x] : 0;
    s[threadIdx.x] = v;
    __syncthreads();
    for (int off = 1; off < 128; off <<= 1) {
        int t = (threadIdx.x >= off) ? s[threadIdx.x - off] : 0;
        __syncthreads();
        s[threadIdx.x] += t;
        __syncthreads();
    }
    if (threadIdx.x < nb) partial[threadIdx.x] = s[threadIdx.x] - v;   // exclusive
    if (threadIdx.x == nb - 1) offs[n] = s[threadIdx.x];               // total
}

__global__ __launch_bounds__(256) void scan_final(const int* __restrict__ deg,
                                                  const int* __restrict__ partial,
                                                  int* __restrict__ offs,
                                                  int* __restrict__ cursor, int n) {
    __shared__ int s[256];
    int i0 = blockIdx.x * 1024 + threadIdx.x * 4;
    int v[4];
    int sum = 0;
#pragma unroll
    for (int r = 0; r < 4; ++r) {
        v[r] = (i0 + r < n) ? deg[i0 + r] : 0;
        sum += v[r];
    }
    s[threadIdx.x] = sum;
    __syncthreads();
    for (int off = 1; off < 256; off <<= 1) {
        int t = (threadIdx.x >= off) ? s[threadIdx.x - off] : 0;
        __syncthreads();
        s[threadIdx.x] += t;
        __syncthreads();
    }
    int excl = s[threadIdx.x] - sum + partial[blockIdx.x];
#pragma unroll
    for (int r = 0; r < 4; ++r) {
        if (i0 + r < n) { offs[i0 + r] = excl; cursor[i0 + r] = excl; }
        excl += v[r];
    }
}

__global__ __launch_bounds__(256) void edge_fill(const int* __restrict__ ei, int E, int n,
                                                 int* __restrict__ cursor,
                                                 int* __restrict__ csr) {
    int e = blockIdx.x * blockDim.x + threadIdx.x;
    int Etot = E + n;
    if (e >= Etot) return;
    int src, dst;
    if (e < E) { src = ei[e]; dst = ei[E + e]; }
    else       { src = e - E; dst = e - E; }
    int pos = atomicAdd(&cursor[dst], 1);
    csr[pos] = src;
}

// -------- Pack W (hi bf16 only) into MFMA-fragment-major layout ----------
// Unit u = kb*CT*64 + ct*64 + lane holds 8 bf16: W[kb*32+(lane>>4)*8+j][ct*16+(lane&15)].

__global__ __launch_bounds__(256) void pack_hi(const float* __restrict__ W,
                                               u16* __restrict__ Bh, int N) {
    int CT = N / 16;
    int idx = blockIdx.x * blockDim.x + threadIdx.x;
    if (idx >= 8 * CT * 64) return;
    int lane = idx & 63;
    int ctkb = idx >> 6;
    int ct = ctkb % CT;
    int kb = ctkb / CT;
    int col = ct * 16 + (lane & 15);
    int k0 = kb * 32 + (lane >> 4) * 8;
#pragma unroll
    for (int j = 0; j < 8; ++j)
        Bh[(size_t)idx * 8 + j] = f2b(W[(size_t)(k0 + j) * N + col]);
}

// -------- U = W·a (per-head score vectors in input space), fp32 exact ----
// U[v][k], v in [0,HEADS) = src heads, [HEADS,2*HEADS) = dst heads.

__global__ __launch_bounds__(64) void make_u(const float* __restrict__ W,
                                             const float* __restrict__ as,
                                             const float* __restrict__ ad,
                                             float* __restrict__ U, int C, int HEADS) {
    int k = blockIdx.x * 64 + threadIdx.x;
    if (k >= 256) return;
    const float* wr = W + (size_t)k * (HEADS * C);
    for (int h = 0; h < HEADS; ++h) {
        float s = 0.f, d = 0.f;
        for (int c = 0; c < C; ++c) {
            float wv = wr[h * C + c];
            s = fmaf(wv, as[h * C + c], s);
            d = fmaf(wv, ad[h * C + c], d);
        }
        U[h * 256 + k] = s;
        U[(HEADS + h) * 256 + k] = d;
    }
}

// -------- Pack U into fragment-major hi/lo (score tile columns) ----------
// Unit idx = kb*64 + lane; col = lane&15 (NS used, rest zero).

__global__ __launch_bounds__(256) void pack_u(const float* __restrict__ U,
                                              u16* __restrict__ Uh,
                                              u16* __restrict__ Ul, int NS) {
    int idx = blockIdx.x * blockDim.x + threadIdx.x;
    if (idx >= 8 * 64) return;
    int lane = idx & 63;
    int kb = idx >> 6;
    int col = lane & 15;
    int k0 = kb * 32 + (lane >> 4) * 8;
#pragma unroll
    for (int j = 0; j < 8; ++j) {
        float v = (col < NS) ? U[col * 256 + k0 + j] : 0.f;
        u16 hi = f2b(v);
        Uh[(size_t)idx * 8 + j] = hi;
        Ul[(size_t)idx * 8 + j] = f2b(v - b2f(hi));
    }
}

// ------- Layer-1 linear (K=3) + fused scores; writes bf16 shadow ---------

__global__ __launch_bounds__(256) void linear1(const float* __restrict__ x,
                                               const float* __restrict__ W,
                                               const float* __restrict__ asrc,
                                               const float* __restrict__ adst,
                                               u16* __restrict__ Hb,
                                               float* __restrict__ ssrc,
                                               float* __restrict__ sdst, int n) {
    int node = blockIdx.x;
    if (node >= n) return;
    int c = threadIdx.x;
    int head = c >> 6, lane = c & 63;
    float x0 = x[node * 3 + 0], x1 = x[node * 3 + 1], x2 = x[node * 3 + 2];
    float v = fmaf(x0, W[c], fmaf(x1, W[256 + c], x2 * W[512 + c]));
    Hb[(size_t)node * 256 + c] = f2b(v);
    float va = v * asrc[c];
    float vb = v * adst[c];
#pragma unroll
    for (int o = 32; o > 0; o >>= 1) {
        va += __shfl_xor(va, o);
        vb += __shfl_xor(vb, o);
    }
    if (lane == 0) { ssrc[node * 4 + head] = va; sdst[node * 4 + head] = vb; }
}

// ------- Lean MFMA GEMM + in-MFMA score tile -----------------------------
// Hb = bf16( (Ahi+Alo) · Whi^T ); scores = g·U via an extra column tile
// (3 MFMAs: ghi·Uhi + glo·Uhi + ghi·Ulo, fp32 acc, abs err ~1e-4).
// A = hi/lo bf16 planes [n][256]; B fragment-major bf16 staged via R12's
// direct global->LDS loop. NS = score vectors (first NS/2 src, rest dst).
// Fragments: A[m=lane&15][k=(lane>>4)*8+j]; D reg r -> row (l>>4)*4+r, col l&15.

template <int CT, int NS>
__global__ __launch_bounds__(256) void gemm_lds(const u16* __restrict__ Ahi,
                                                const u16* __restrict__ Alo,
                                                const u16* __restrict__ Bh,
                                                const u16* __restrict__ Uh,
                                                const u16* __restrict__ Ul,
                                                u16* __restrict__ Hb,
                                                float* __restrict__ sOs,
                                                float* __restrict__ sOd, int n) {
    constexpr int UN = CT * 64;                 // 16-byte units per k-slice
    __shared__ __align__(16) u16 sB[UN * 8];
    int t = threadIdx.x;
    int w = t >> 6, l = t & 63;
    int m0 = blockIdx.x * 64 + w * 16;
    int lm = l & 15, q = l >> 4;
    floatx4 acc[CT] = {};
    floatx4 accS = {};
    int arow = min(m0 + lm, n - 1);
    const u16* ahp = Ahi + (size_t)arow * 256 + q * 8;
    const u16* alp = Alo + (size_t)arow * 256 + q * 8;

    for (int kb = 0; kb < 8; ++kb) {
        __syncthreads();
        // stage B k-slice, coalesced, one value live at a time (no spill)
        for (int u = t; u < UN; u += 256)
            *(uint4*)&sB[u * 8] = *(const uint4*)&Bh[((size_t)kb * UN + u) * 8];
        // A fragments + U score-tile fragments (overlap staging)
        bf16x8 ahi = *(const bf16x8*)(ahp + kb * 32);
        bf16x8 alo = *(const bf16x8*)(alp + kb * 32);
        bf16x8 uhi = *(const bf16x8*)&Uh[(size_t)(kb * 64 + l) * 8];
        bf16x8 ulo = *(const bf16x8*)&Ul[(size_t)(kb * 64 + l) * 8];
        __syncthreads();
#pragma unroll
        for (int ct = 0; ct < CT; ++ct) {
            bf16x8 bhi = *(const bf16x8*)&sB[(ct * 64 + l) * 8];
            acc[ct] = __builtin_amdgcn_mfma_f32_16x16x32_bf16(ahi, bhi, acc[ct], 0, 0, 0);
            acc[ct] = __builtin_amdgcn_mfma_f32_16x16x32_bf16(alo, bhi, acc[ct], 0, 0, 0);
        }
        // score tile: s = ghi·Uhi + glo·Uhi + ghi·Ulo
        accS = __builtin_amdgcn_mfma_f32_16x16x32_bf16(ahi, uhi, accS, 0, 0, 0);
        accS = __builtin_amdgcn_mfma_f32_16x16x32_bf16(alo, uhi, accS, 0, 0, 0);
        accS = __builtin_amdgcn_mfma_f32_16x16x32_bf16(ahi, ulo, accS, 0, 0, 0);
    }
#pragma unroll
    for (int ct = 0; ct < CT; ++ct)
#pragma unroll
        for (int r = 0; r < 4; ++r) {
            int row = m0 + q * 4 + r;
            if (row < n)
                Hb[(size_t)row * (CT * 16) + ct * 16 + lm] = f2b(acc[ct][r]);
        }
    if (lm < NS) {
#pragma unroll
        for (int r = 0; r < 4; ++r) {
            int row = m0 + q * 4 + r;
            if (row < n) {
                if (lm < NS / 2) sOs[row * (NS / 2) + lm] = accS[r];
                else             sOd[row * (NS / 2) + (lm - NS / 2)] = accS[r];
            }
        }
    }
}

// ---------------- Merged 4-head aggregation (layers 1 & 2) ----------------
// One wave per dst node; bf16 value gathers, fp32 logits/accum.
// Slim epilogue: hi/lo bf16 planes of the relu'd output only.

__global__ __launch_bounds__(256) void gat_aggregate_m4(const u16* __restrict__ Hb,
                                                        const float* __restrict__ ssrc,
                                                        const float* __restrict__ sdst,
                                                        const int* __restrict__ offs,
                                                        const int* __restrict__ csr,
                                                        const float* __restrict__ bias,
                                                        u16* __restrict__ Ghi,
                                                        u16* __restrict__ Glo, int n) {
    int node = blockIdx.x * 4 + (threadIdx.x >> 6);
    int lane = threadIdx.x & 63;
    if (node >= n) return;
    const int hB = lane & 3;
    const int eL = lane >> 2;
    const int hA = lane >> 4;
    int beg = offs[node], end = offs[node + 1];
    float sd = sdst[node * 4 + hB];
    float m = -INFINITY, l = 0.f;
    float4 acc = make_float4(0.f, 0.f, 0.f, 0.f);

    for (int base = beg; base < end; base += 16) {
        int j = base + eL;
        bool valid = (j < end);
        int sj = valid ? csr[j] : 0;
        float logit = -INFINITY;
        if (valid) {
            float xv = ssrc[sj * 4 + hB] + sd;
            logit = (xv > 0.f) ? xv : NEG_SLOPE * xv;
        }
        float cm = logit;
        cm = fmaxf(cm, __shfl_xor(cm, 4));
        cm = fmaxf(cm, __shfl_xor(cm, 8));
        cm = fmaxf(cm, __shfl_xor(cm, 16));
        cm = fmaxf(cm, __shfl_xor(cm, 32));
        float nm = fmaxf(m, cm);
        float scale = __expf(m - nm);       // m=-inf -> 0
        float ex = valid ? __expf(logit - nm) : 0.f;
        float es = ex;
        es += __shfl_xor(es, 4);
        es += __shfl_xor(es, 8);
        es += __shfl_xor(es, 16);
        es += __shfl_xor(es, 32);
        l = l * scale + es;
        m = nm;
        float sA = __shfl(scale, hA);
        acc.x *= sA; acc.y *= sA; acc.z *= sA; acc.w *= sA;

        int cnt = min(16, end - base);
        for (int t = 0; t < cnt; t += 4) {
#pragma unroll
            for (int u = 0; u < 4; ++u) {
                int tt = t + u;
                float a = __shfl(ex, tt * 4 + hA);   // 0 for invalid edges
                int s = __shfl(sj, tt * 4);          // 0 for invalid (safe addr)
                ushort4 hv = *(const ushort4*)&Hb[(size_t)s * 256 + lane * 4];
                acc.x = fmaf(a, b2f(hv.x), acc.x);
                acc.y = fmaf(a, b2f(hv.y), acc.y);
                acc.z = fmaf(a, b2f(hv.z), acc.z);
                acc.w = fmaf(a, b2f(hv.w), acc.w);
            }
        }
    }
    float lf = __shfl(l, hA);
    float inv = 1.f / lf;
    const float4 bv = *(const float4*)&bias[lane * 4];
    float4 o;
    o.x = fmaxf(fmaf(acc.x, inv, bv.x), 0.f);   // relu
    o.y = fmaxf(fmaf(acc.y, inv, bv.y), 0.f);
    o.z = fmaxf(fmaf(acc.z, inv, bv.z), 0.f);
    o.w = fmaxf(fmaf(acc.w, inv, bv.w), 0.f);
    ushort4 h4, l4;
    h4.x = f2b(o.x); l4.x = f2b(o.x - b2f(h4.x));
    h4.y = f2b(o.y); l4.y = f2b(o.y - b2f(h4.y));
    h4.z = f2b(o.z); l4.z = f2b(o.z - b2f(h4.z));
    h4.w = f2b(o.w); l4.w = f2b(o.w - b2f(h4.w));
    *(ushort4*)&Ghi[(size_t)node * 256 + lane * 4] = h4;
    *(ushort4*)&Glo[(size_t)node * 256 + lane * 4] = l4;
}

// ---------------- Single-head aggregation (layer 3, C=32, no relu) --------

__global__ __launch_bounds__(256) void gat_aggregate_h1(const u16* __restrict__ Hb,
                                                        const float* __restrict__ ssrc,
                                                        const float* __restrict__ sdst,
                                                        const int* __restrict__ offs,
                                                        const int* __restrict__ csr,
                                                        const float* __restrict__ bias,
                                                        float* __restrict__ out, int n) {
    int node = blockIdx.x * 4 + (threadIdx.x >> 6);
    int lane = threadIdx.x & 63;
    if (node >= n) return;
    int beg = offs[node], end = offs[node + 1];
    float sd = sdst[node];
    float m = -INFINITY, l = 0.f, acc = 0.f;

    for (int base = beg; base < end; base += 64) {
        int j = base + lane;
        bool valid = (j < end);
        int sj = valid ? csr[j] : 0;
        float logit = -INFINITY;
        if (valid) {
            float xv = ssrc[sj] + sd;
            logit = (xv > 0.f) ? xv : NEG_SLOPE * xv;
        }
        float cm = logit;
#pragma unroll
        for (int o = 32; o > 0; o >>= 1) cm = fmaxf(cm, __shfl_xor(cm, o));
        float nm = fmaxf(m, cm);
        float scale = __expf(m - nm);
        float ex = valid ? __expf(logit - nm) : 0.f;
        float es = ex;
#pragma unroll
        for (int o = 32; o > 0; o >>= 1) es += __shfl_xor(es, o);
        l = l * scale + es;
        m = nm;
        acc *= scale;
        int cnt = min(64, end - base);
        for (int t = 0; t < cnt; t += 4) {
#pragma unroll
            for (int u = 0; u < 4; ++u) {
                float a = __shfl(ex, t + u);
                int s = __shfl(sj, t + u);
                if (lane < 32) acc = fmaf(a, b2f(Hb[(size_t)s * 32 + lane]), acc);
            }
        }
    }
    if (lane < 32) out[(size_t)node * 32 + lane] = acc / l + bias[lane];
}

// ---------------- Launch ----------------

extern "C" void kernel_launch(void* const* d_in, const int* in_sizes, int n_in,
                              void* d_out, int out_size, void* d_ws, size_t ws_size,
                              hipStream_t stream) {
    const float* x   = (const float*)d_in[0];
    const int*   ei  = (const int*)d_in[1];
    const float* W1  = (const float*)d_in[2];
    const float* as1 = (const float*)d_in[3];
    const float* ad1 = (const float*)d_in[4];
    const float* b1  = (const float*)d_in[5];
    const float* W2  = (const float*)d_in[6];
    const float* as2 = (const float*)d_in[7];
    const float* ad2 = (const float*)d_in[8];
    const float* b2  = (const float*)d_in[9];
    const float* W3  = (const float*)d_in[10];
    const float* as3 = (const float*)d_in[11];
    const float* ad3 = (const float*)d_in[12];
    const float* b3  = (const float*)d_in[13];
    float* out = (float*)d_out;

    const int n = in_sizes[0] / 3;     // 50000
    const int E = in_sizes[1] / 2;     // 400000
    const int Etot = E + n;            // with self-loops

    // workspace layout
    char* ws = (char*)d_ws;
    u16* Hb   = (u16*)ws;    ws += (size_t)n * 256 * sizeof(u16);   // 25.6 MB shadow
    u16* Ghi  = (u16*)ws;    ws += (size_t)n * 256 * sizeof(u16);   // 25.6 MB
    u16* Glo  = (u16*)ws;    ws += (size_t)n * 256 * sizeof(u16);   // 25.6 MB
    u16* Hb3  = (u16*)ws;    ws += (size_t)n * 32 * sizeof(u16);    // 3.2 MB
    u16* B2h  = (u16*)ws;    ws += (size_t)8 * 16 * 64 * 8 * sizeof(u16);  // 128 KB
    u16* B3h  = (u16*)ws;    ws += (size_t)8 * 2 * 64 * 8 * sizeof(u16);   // 16 KB
    float* U2 = (float*)ws;  ws += (size_t)8 * 256 * sizeof(float);
    float* U3 = (float*)ws;  ws += (size_t)2 * 256 * sizeof(float);
    u16* U2h  = (u16*)ws;    ws += (size_t)8 * 64 * 8 * sizeof(u16);       // 8 KB
    u16* U2l  = (u16*)ws;    ws += (size_t)8 * 64 * 8 * sizeof(u16);
    u16* U3h  = (u16*)ws;    ws += (size_t)8 * 64 * 8 * sizeof(u16);
    u16* U3l  = (u16*)ws;    ws += (size_t)8 * 64 * 8 * sizeof(u16);
    float* sAs = (float*)ws; ws += (size_t)n * 4 * sizeof(float);
    float* sAd = (float*)ws; ws += (size_t)n * 4 * sizeof(float);
    float* sBs = (float*)ws; ws += (size_t)n * 4 * sizeof(float);
    float* sBd = (float*)ws; ws += (size_t)n * 4 * sizeof(float);
    float* sCs = (float*)ws; ws += (size_t)n * sizeof(float);
    float* sCd = (float*)ws; ws += (size_t)n * sizeof(float);
    int* deg    = (int*)ws;  ws += (size_t)n * sizeof(int);
    int* offs   = (int*)ws;  ws += (size_t)(n + 1) * sizeof(int) + 12;
    int* cursor = (int*)ws;  ws += (size_t)n * sizeof(int);
    int* partial = (int*)ws; ws += (size_t)128 * sizeof(int);
    int* csr    = (int*)ws;  ws += (size_t)Etot * sizeof(int);   // keep csr LAST

    // ---- CSR build (by dst) ----
    hipMemsetAsync(deg, 0, (size_t)n * sizeof(int), stream);
    int eblocks = (Etot + 255) / 256;
    edge_count<<<eblocks, 256, 0, stream>>>(ei, E, n, deg);
    int sb = (n + 1023) / 1024;
    scan_partials<<<sb, 256, 0, stream>>>(deg, partial, n);
    scan_mid<<<1, 128, 0, stream>>>(partial, sb, offs, n);
    scan_final<<<sb, 256, 0, stream>>>(deg, partial, offs, cursor, n);
    edge_fill<<<eblocks, 256, 0, stream>>>(ei, E, n, cursor, csr);

    // ---- Weight prep ----
    pack_hi<<<(8 * 16 * 64 + 255) / 256, 256, 0, stream>>>(W2, B2h, 256);
    pack_hi<<<(8 * 2 * 64 + 255) / 256, 256, 0, stream>>>(W3, B3h, 32);
    make_u<<<4, 64, 0, stream>>>(W2, as2, ad2, U2, 64, 4);
    make_u<<<4, 64, 0, stream>>>(W3, as3, ad3, U3, 32, 1);
    pack_u<<<2, 256, 0, stream>>>(U2, U2h, U2l, 8);
    pack_u<<<2, 256, 0, stream>>>(U3, U3h, U3l, 2);

    int nb4 = (n + 3) / 4;
    int nb64 = (n + 63) / 64;

    // ---- Layer 1: 3 -> (4 x 64), concat, relu ----
    linear1<<<n, 256, 0, stream>>>(x, W1, as1, ad1, Hb, sAs, sAd, n);
    gat_aggregate_m4<<<nb4, 256, 0, stream>>>(Hb, sAs, sAd, offs, csr, b1, Ghi, Glo, n);

    // ---- Layer 2: 256 -> (4 x 64), concat, relu (+ layer-2 scores) ----
    gemm_lds<16, 8><<<nb64, 256, 0, stream>>>(Ghi, Glo, B2h, U2h, U2l, Hb, sBs, sBd, n);
    gat_aggregate_m4<<<nb4, 256, 0, stream>>>(Hb, sBs, sBd, offs, csr, b2, Ghi, Glo, n);

    // ---- Layer 3: 256 -> (1 x 32), mean(=identity), no relu (+ scores) ----
    gemm_lds<2, 2><<<nb64, 256, 0, stream>>>(Ghi, Glo, B3h, U3h, U3l, Hb3, sCs, sCd, n);
    gat_aggregate_h1<<<nb4, 256, 0, stream>>>(Hb3, sCs, sCd, offs, csr, b3, out, n);
}